// Round 3
// baseline (223.030 us; speedup 1.0000x reference)
//
#include <hip/hip_runtime.h>
#include <hip/hip_bf16.h>
#include <stdint.h>

#define M_DIM 16384   // 8 * 2048
#define N_DIM 2048    // OUT_F
#define K_DIM 2048    // IN_F

typedef __attribute__((ext_vector_type(8))) __bf16 bf16x8;
typedef __attribute__((ext_vector_type(4))) float f32x4;

__device__ __forceinline__ unsigned short f2bf(float f) {
  unsigned int u = __builtin_bit_cast(unsigned int, f);
  u += 0x7FFFu + ((u >> 16) & 1u);   // round-to-nearest-even
  return (unsigned short)(u >> 16);
}

__device__ __forceinline__ float sigmoidf_(float x) {
  return 1.0f / (1.0f + __expf(-x));
}

// ---------------- kernel 1: X f32 -> bf16 ----------------
__global__ __launch_bounds__(256) void convert_x(const float4* __restrict__ x,
                                                 uint4* __restrict__ xb) {
  int idx = blockIdx.x * 256 + threadIdx.x;   // one uint4 (8 bf16) per thread
  float4 a = x[idx * 2];
  float4 b = x[idx * 2 + 1];
  uint4 r;
  r.x = (unsigned)f2bf(a.x) | ((unsigned)f2bf(a.y) << 16);
  r.y = (unsigned)f2bf(a.z) | ((unsigned)f2bf(a.w) << 16);
  r.z = (unsigned)f2bf(b.x) | ((unsigned)f2bf(b.y) << 16);
  r.w = (unsigned)f2bf(b.z) | ((unsigned)f2bf(b.w) << 16);
  xb[idx] = r;
}

// ---------------- kernel 2: weight materialization ----------------
__global__ __launch_bounds__(256) void make_w(const float4* __restrict__ pw,
                                              const float4* __restrict__ nw,
                                              const float* __restrict__ exps,
                                              const float* __restrict__ maskw,
                                              const float* __restrict__ scale,
                                              unsigned short* __restrict__ wout) {
  int idx = blockIdx.x * 256 + threadIdx.x;   // flat (o*K + i)
  float4 p = pw[idx];
  float4 n = nw[idx];
  float s = scale[0];
  float c0 = sigmoidf_(maskw[0]) * exps[0] * s;
  float c1 = sigmoidf_(maskw[1]) * exps[1] * s;
  float c2 = sigmoidf_(maskw[2]) * exps[2] * s;
  float c3 = sigmoidf_(maskw[3]) * exps[3] * s;
  float w = (sigmoidf_(p.x) - sigmoidf_(n.x)) * c0
          + (sigmoidf_(p.y) - sigmoidf_(n.y)) * c1
          + (sigmoidf_(p.z) - sigmoidf_(n.z)) * c2
          + (sigmoidf_(p.w) - sigmoidf_(n.w)) * c3;
  wout[idx] = f2bf(w);
}

// ---------------- kernel 3: bias ----------------
__global__ __launch_bounds__(256) void make_bias(const float* __restrict__ pb,
                                                 const float* __restrict__ nb,
                                                 const float* __restrict__ bexps,
                                                 const float* __restrict__ bscale,
                                                 float* __restrict__ bias) {
  int o = blockIdx.x * 256 + threadIdx.x;
  if (o < N_DIM) {
    float x = 0.f;
#pragma unroll
    for (int n = 0; n < 4; ++n) x += (pb[o * 4 + n] - nb[o * 4 + n]) * bexps[n];
    float xc = fminf(fmaxf(x, -1.f), 1.f);
    float mag = rintf(fabsf(xc) * 15.f) * (1.f / 15.f);
    float sgn = (xc > 0.f) ? 1.f : ((xc < 0.f) ? -1.f : 0.f);
    bias[o] = mag * sgn * bscale[0];
  }
}

// ---------------- kernel 4: 256x256 8-phase GEMM, deep pipeline ----------------
// out[m][o] = sum_k X[m][k]*W[o][k] + bias[o]
// BM=BN=256, BK=64, 512 threads (8 waves 2Mx4N), 128 KiB LDS double-buffered.
//
// Staging rounds per K-tile (one gload_lds per thread each, 8 KB, 64 rows):
//   R0: A{0-63}    R1: A{128-191}   R2: B{0-31,64-95}   R3: B{128-159,192-223}
//   R4: B{32-63,96-127}  R5: B{160-191,224-255}  R6: A{64-127}  R7: A{192-255}
// Consumption: P0 reads R0-R3(t); P1 reads R4,R5(t); P2 reads R6,R7(t); P3 none.
//
// DEEP schedule (R2 post-mortem: 3-phase gate lookahead stalled every tile):
//   P0(t) issues R4-R7(t+1) -> buf q   (consumed P1/P2(t+1): 5-6 phases away)
//   P3(t) issues R0-R3(t+2) -> buf p   (p fully read after end-P2 barrier;
//                                       consumed P0(t+2): 5 phases away)
// Gates (derived from issue stream, uniform via wrap-around staging):
//   end-P0: VMCNT(10)  [newer than R4R5(t): R6R7(t)+R0-R3(t+1)+R4-R7(t+1)=10]
//   end-P1: VMCNT(8)   [newer than R6R7(t): 8]
//   end-P2: none       [P3 reads nothing]
//   end-P3: VMCNT(8)   [newer than R0-R3(t+1): R4-R7(t+1)+R0-R3(t+2)=8]
// Max 12 loads in flight; never drained in the loop. Tail tiles stage
// wrapped k-index ((t+k)&31) into never-read buffers: keeps counts exact.

#define BM 256
#define BN 256
#define BK 64
#define NT (K_DIM / BK)   // 32

__device__ __forceinline__ void gload16(const void* g, void* l) {
  __builtin_amdgcn_global_load_lds(
      (const __attribute__((address_space(1))) unsigned int*)g,
      (__attribute__((address_space(3))) unsigned int*)l, 16, 0, 0);
}

#define VMCNT(n) asm volatile("s_waitcnt vmcnt(" #n ")" ::: "memory")
#define BAR() __builtin_amdgcn_s_barrier()

__global__ __launch_bounds__(512, 2) void gemm_bias(const unsigned short* __restrict__ X,
                                                    const unsigned short* __restrict__ W,
                                                    const float* __restrict__ bias,
                                                    float* __restrict__ out) {
  __shared__ unsigned short sA[2][BM * BK];   // 64 KiB
  __shared__ unsigned short sB[2][BN * BK];   // 64 KiB

  const int tid = threadIdx.x;
  // T1: bijective XCD swizzle (512 % 8 == 0). Each XCD: 8bm x 8bn chunk,
  // bn fastest -> concurrent 32 blocks ~ 4bm x 8bn: A panels (4 MB) L2-resident,
  // same-bn blocks fetch B K-slabs in near-lockstep (transient L2 hits).
  const int swz = ((int)blockIdx.x & 7) * 64 + ((int)blockIdx.x >> 3);
  const int bm = swz >> 3;      // 0..63
  const int bn = swz & 7;       // 0..7
  const int row0 = bm * BM, col0 = bn * BN;

  const int w = tid >> 6, l = tid & 63;
  const int wr = w >> 2;        // 0..1  (M wave group)
  const int wc = w & 3;         // 0..3  (N wave group)
  const int lr = l & 15;
  const int lk4 = l >> 4;       // 0..3
  const int l7 = l & 7;

  const unsigned short* Ag = X + (size_t)row0 * K_DIM;
  const unsigned short* Bg = W + (size_t)col0 * K_DIM;

  // staging geometry: thread t -> row rb+((t>>3)&31), global col16 pre-swizzled
  const int srl = (tid >> 3) & 31;
  const int sc16 = (tid & 7) ^ ((tid >> 3) & 7);      // inverse-swizzled source
  const int shi = tid >> 8;                           // wave-uniform chunk select
  const int slin = ((tid >> 3) & 24) * 64 + (tid & 63) * 8;  // linear LDS dest

  auto stage = [&](unsigned short* lbase, const unsigned short* gbase,
                   int rb0, int rb1, int tk) {
    int rb = shi ? rb1 : rb0;
    int trow = rb + srl;
    gload16(gbase + (size_t)trow * K_DIM + tk * BK + sc16 * 8,
            lbase + rb * 64 + slin);
  };

  auto rdA = [&](const unsigned short* base, int mf, int ks) -> bf16x8 {
    int trow = wr * 128 + mf * 16 + lr;
    int c16l = (ks * 4 + lk4) ^ l7;
    return *(const bf16x8*)&base[trow * 64 + c16l * 8];
  };
  auto rdB = [&](const unsigned short* base, int nf, int ks) -> bf16x8 {
    int trow = wc * 64 + nf * 16 + lr;
    int c16l = (ks * 4 + lk4) ^ l7;
    return *(const bf16x8*)&base[trow * 64 + c16l * 8];
  };

  f32x4 acc[8][4] = {};
  bf16x8 a[4][2], b[4][2];

#define PHASE_MFMA(mh, nh)                                                    \
  __builtin_amdgcn_s_setprio(1);                                              \
  _Pragma("unroll") for (int i = 0; i < 4; ++i)                               \
  _Pragma("unroll") for (int j = 0; j < 2; ++j)                               \
  _Pragma("unroll") for (int ks = 0; ks < 2; ++ks)                            \
      acc[(mh) * 4 + i][(nh) * 2 + j] = __builtin_amdgcn_mfma_f32_16x16x32_bf16( \
          a[i][ks], b[(nh) * 2 + j][ks], acc[(mh) * 4 + i][(nh) * 2 + j], 0, 0, 0); \
  __builtin_amdgcn_s_setprio(0);

  // ---- prologue: R0-R7(0) -> buf0, R0-R3(1) -> buf1  (12 loads in flight)
  stage(sA[0], Ag, 0, 32, 0);     // R0(0)
  stage(sA[0], Ag, 128, 160, 0);  // R1(0)
  stage(sB[0], Bg, 0, 64, 0);     // R2(0)
  stage(sB[0], Bg, 128, 192, 0);  // R3(0)
  stage(sB[0], Bg, 32, 96, 0);    // R4(0)
  stage(sB[0], Bg, 160, 224, 0);  // R5(0)
  stage(sA[0], Ag, 64, 96, 0);    // R6(0)
  stage(sA[0], Ag, 192, 224, 0);  // R7(0)
  stage(sA[1], Ag, 0, 32, 1);     // R0(1)
  stage(sA[1], Ag, 128, 160, 1);  // R1(1)
  stage(sB[1], Bg, 0, 64, 1);     // R2(1)
  stage(sB[1], Bg, 128, 192, 1);  // R3(1)
  VMCNT(8);   // R0-R3(0) complete
  BAR();

  for (int t = 0; t < NT; ++t) {
    const int p = t & 1, q = p ^ 1;
    const int t1 = (t + 1) & (NT - 1);   // wrap: tail stages harmless data,
    const int t2 = (t + 2) & (NT - 1);   // keeps vmcnt accounting uniform
    const unsigned short* pa = sA[p];
    const unsigned short* pb = sB[p];

    // ---- P0: read A(mh0)+B(nf0,1) of t; issue R4-R7(t+1) -> buf q
#pragma unroll
    for (int i = 0; i < 4; ++i)
#pragma unroll
      for (int ks = 0; ks < 2; ++ks) a[i][ks] = rdA(pa, i, ks);
#pragma unroll
    for (int j = 0; j < 2; ++j)
#pragma unroll
      for (int ks = 0; ks < 2; ++ks) b[j][ks] = rdB(pb, j, ks);
    stage(sB[q], Bg, 32, 96, t1);    // R4(t+1)
    stage(sB[q], Bg, 160, 224, t1);  // R5(t+1)
    stage(sA[q], Ag, 64, 96, t1);    // R6(t+1)
    stage(sA[q], Ag, 192, 224, t1);  // R7(t+1)
    BAR();
    PHASE_MFMA(0, 0);
    VMCNT(10);                       // R4,R5(t) done (issued P0(t-1), 5 phases ago)
    BAR();

    // ---- P1: read B(nf2,3) of t
#pragma unroll
    for (int j = 2; j < 4; ++j)
#pragma unroll
      for (int ks = 0; ks < 2; ++ks) b[j][ks] = rdB(pb, j, ks);
    BAR();
    PHASE_MFMA(0, 1);
    VMCNT(8);                        // R6,R7(t) done (6 phases ago)
    BAR();

    // ---- P2: read A(mh1) of t   (last reads of buf p)
#pragma unroll
    for (int i = 0; i < 4; ++i)
#pragma unroll
      for (int ks = 0; ks < 2; ++ks) a[i][ks] = rdA(pa, 4 + i, ks);
    BAR();
    PHASE_MFMA(1, 0);
    BAR();                           // no gate: P3 reads nothing

    // ---- P3: buf p fully consumed -> issue R0-R3(t+2) into it
    stage(sA[p], Ag, 0, 32, t2);     // R0(t+2)
    stage(sA[p], Ag, 128, 160, t2);  // R1(t+2)
    stage(sB[p], Bg, 0, 64, t2);     // R2(t+2)
    stage(sB[p], Bg, 128, 192, t2);  // R3(t+2)
    BAR();
    PHASE_MFMA(1, 1);
    VMCNT(8);                        // R0-R3(t+1) done (5 phases ago)
    BAR();
  }

  // ---- epilogue: bias + store (C/D layout: col=lane&15, row=(lane>>4)*4+reg)
  float bv[4];
#pragma unroll
  for (int nf = 0; nf < 4; ++nf) bv[nf] = bias[col0 + wc * 64 + nf * 16 + lr];
  const int orow = lk4 * 4;
#pragma unroll
  for (int mf = 0; mf < 8; ++mf) {
#pragma unroll
    for (int nf = 0; nf < 4; ++nf) {
      const int colg = col0 + wc * 64 + nf * 16 + lr;
#pragma unroll
      for (int r = 0; r < 4; ++r) {
        int rowg = row0 + wr * 128 + mf * 16 + orow + r;
        out[(size_t)rowg * N_DIM + colg] = acc[mf][nf][r] + bv[nf];
      }
    }
  }
#undef PHASE_MFMA
}

// ---------------- launch ----------------
extern "C" void kernel_launch(void* const* d_in, const int* in_sizes, int n_in,
                              void* d_out, int out_size, void* d_ws, size_t ws_size,
                              hipStream_t stream) {
  const float* input  = (const float*)d_in[0];
  const float* pweight = (const float*)d_in[1];
  const float* nweight = (const float*)d_in[2];
  const float* exps   = (const float*)d_in[3];
  const float* bexps  = (const float*)d_in[4];
  const float* maskw  = (const float*)d_in[5];
  const float* scale  = (const float*)d_in[6];
  const float* pbias  = (const float*)d_in[7];
  const float* nbias  = (const float*)d_in[8];
  const float* bscale = (const float*)d_in[9];
  float* out = (float*)d_out;

  unsigned short* Xb = (unsigned short*)d_ws;                                        // 64 MB
  unsigned short* Wb = (unsigned short*)((char*)d_ws + (size_t)M_DIM * K_DIM * 2);   // 8 MB
  float* bias = (float*)((char*)d_ws + (size_t)M_DIM * K_DIM * 2 + (size_t)N_DIM * K_DIM * 2);

  convert_x<<<(M_DIM * (size_t)K_DIM) / 8 / 256, 256, 0, stream>>>((const float4*)input, (uint4*)Xb);
  make_w<<<((size_t)N_DIM * K_DIM) / 256, 256, 0, stream>>>(
      (const float4*)pweight, (const float4*)nweight, exps, maskw, scale, Wb);
  make_bias<<<(N_DIM + 255) / 256, 256, 0, stream>>>(pbias, nbias, bexps, bscale, bias);

  dim3 grid((M_DIM / BM) * (N_DIM / BN));   // 64 * 8 = 512
  gemm_bias<<<grid, 512, 0, stream>>>(Xb, Wb, bias, out);
}

// Round 4
// 211.910 us; speedup vs baseline: 1.0525x; 1.0525x over previous
//
#include <hip/hip_runtime.h>
#include <hip/hip_bf16.h>
#include <stdint.h>

#define M_DIM 16384   // 8 * 2048
#define N_DIM 2048    // OUT_F
#define K_DIM 2048    // IN_F

typedef __attribute__((ext_vector_type(8))) __bf16 bf16x8;
typedef __attribute__((ext_vector_type(4))) float f32x4;

__device__ __forceinline__ unsigned short f2bf(float f) {
  unsigned int u = __builtin_bit_cast(unsigned int, f);
  u += 0x7FFFu + ((u >> 16) & 1u);   // round-to-nearest-even
  return (unsigned short)(u >> 16);
}

__device__ __forceinline__ float sigmoidf_(float x) {
  return 1.0f / (1.0f + __expf(-x));
}

// ---------------- kernel 1: X f32 -> bf16 ----------------
__global__ __launch_bounds__(256) void convert_x(const float4* __restrict__ x,
                                                 uint4* __restrict__ xb) {
  int idx = blockIdx.x * 256 + threadIdx.x;   // one uint4 (8 bf16) per thread
  float4 a = x[idx * 2];
  float4 b = x[idx * 2 + 1];
  uint4 r;
  r.x = (unsigned)f2bf(a.x) | ((unsigned)f2bf(a.y) << 16);
  r.y = (unsigned)f2bf(a.z) | ((unsigned)f2bf(a.w) << 16);
  r.z = (unsigned)f2bf(b.x) | ((unsigned)f2bf(b.y) << 16);
  r.w = (unsigned)f2bf(b.z) | ((unsigned)f2bf(b.w) << 16);
  xb[idx] = r;
}

// ---------------- kernel 2: weight materialization ----------------
__global__ __launch_bounds__(256) void make_w(const float4* __restrict__ pw,
                                              const float4* __restrict__ nw,
                                              const float* __restrict__ exps,
                                              const float* __restrict__ maskw,
                                              const float* __restrict__ scale,
                                              unsigned short* __restrict__ wout) {
  int idx = blockIdx.x * 256 + threadIdx.x;   // flat (o*K + i)
  float4 p = pw[idx];
  float4 n = nw[idx];
  float s = scale[0];
  float c0 = sigmoidf_(maskw[0]) * exps[0] * s;
  float c1 = sigmoidf_(maskw[1]) * exps[1] * s;
  float c2 = sigmoidf_(maskw[2]) * exps[2] * s;
  float c3 = sigmoidf_(maskw[3]) * exps[3] * s;
  float w = (sigmoidf_(p.x) - sigmoidf_(n.x)) * c0
          + (sigmoidf_(p.y) - sigmoidf_(n.y)) * c1
          + (sigmoidf_(p.z) - sigmoidf_(n.z)) * c2
          + (sigmoidf_(p.w) - sigmoidf_(n.w)) * c3;
  wout[idx] = f2bf(w);
}

// ---------------- kernel 3: bias ----------------
__global__ __launch_bounds__(256) void make_bias(const float* __restrict__ pb,
                                                 const float* __restrict__ nb,
                                                 const float* __restrict__ bexps,
                                                 const float* __restrict__ bscale,
                                                 float* __restrict__ bias) {
  int o = blockIdx.x * 256 + threadIdx.x;
  if (o < N_DIM) {
    float x = 0.f;
#pragma unroll
    for (int n = 0; n < 4; ++n) x += (pb[o * 4 + n] - nb[o * 4 + n]) * bexps[n];
    float xc = fminf(fmaxf(x, -1.f), 1.f);
    float mag = rintf(fabsf(xc) * 15.f) * (1.f / 15.f);
    float sgn = (xc > 0.f) ? 1.f : ((xc < 0.f) ? -1.f : 0.f);
    bias[o] = mag * sgn * bscale[0];
  }
}

// ---------------- kernel 4: 256x256 GEMM, fragment-read-ahead pipeline ------
// out[m][o] = sum_k X[m][k]*W[o][k] + bias[o]
// BM=BN=256, BK=64, 512 threads (8 waves 2Mx4N), 128 KiB LDS double-buffered.
//
// R3 post-mortem: ds_read -> barrier -> MFMA within one phase SERIALIZES the
// LDS pipe (2000cy/tile) with the matrix pipe (2480cy/tile) -> 5800cy/tile.
// Fix: each phase's MFMA consumes fragments ds_read in the PREVIOUS phase;
// this phase's reads (for the next phase) fly under the MFMA (compiler emits
// counted lgkmcnt since MFMA has no dep on them). One barrier per phase.
//
// Rounds (one gload_lds/thread, 64 rows): R0:A{0-63} R1:A{128-191}
// R2:B{0-31,64-95} R3:B{128-159,192-223} R4:B{32-63,96-127}
// R5:B{160-191,224-255} R6:A{64-127} R7:A{192-255}
// Fragment needs: a-mh0<-R0R1, b01<-R2R3, b23<-R4R5, a-mh1<-R6R7.
//
// Steady-state phase map (tile t; p=t&1 current buf, q=other):
//   P0: read b23(t)[p/R4R5]   stage R4R5(t+1)->q  MFMA(mh0,nh0)  VMCNT(6) BAR
//   P1: read a-mh1(t)[p/R6R7] stage R6R7(t+1)->q  MFMA(mh0,nh1)  VMCNT(6) BAR
//   P2: read a-mh0(t+1)[q/R0R1] stage R0R1(t+2)->p MFMA(mh1,nh0) VMCNT(6) BAR
//   P3: read b01(t+1)[q/R2R3] stage R2R3(t+2)->p  MFMA(mh1,nh1)  VMCNT(6) BAR
// Every stage-pair is consumed exactly 4 phases after issue; 8 loads in
// flight; uniform VMCNT(6) retires exactly the pair the next phase reads
// (verified for all four phases). Buffer-region WAR distances >= 4 barriers.
// Tail: wrapped indices (mod NT) keep counting uniform; junk reads land in
// dead registers.

#define BM 256
#define BN 256
#define BK 64
#define NT (K_DIM / BK)   // 32

__device__ __forceinline__ void gload16(const void* g, void* l) {
  __builtin_amdgcn_global_load_lds(
      (const __attribute__((address_space(1))) unsigned int*)g,
      (__attribute__((address_space(3))) unsigned int*)l, 16, 0, 0);
}

#define VMCNT(n) asm volatile("s_waitcnt vmcnt(" #n ")" ::: "memory")
#define BAR() __builtin_amdgcn_s_barrier()

__global__ __launch_bounds__(512, 2) void gemm_bias(const unsigned short* __restrict__ X,
                                                    const unsigned short* __restrict__ W,
                                                    const float* __restrict__ bias,
                                                    float* __restrict__ out) {
  __shared__ unsigned short sA[2][BM * BK];   // 64 KiB
  __shared__ unsigned short sB[2][BN * BK];   // 64 KiB

  const int tid = threadIdx.x;
  // T1: bijective XCD swizzle (512 % 8 == 0): each XCD an 8bm x 8bn chunk.
  const int swz = ((int)blockIdx.x & 7) * 64 + ((int)blockIdx.x >> 3);
  const int bm = swz >> 3;      // 0..63
  const int bn = swz & 7;       // 0..7
  const int row0 = bm * BM, col0 = bn * BN;

  const int w = tid >> 6, l = tid & 63;
  const int wr = w >> 2;        // 0..1  (M wave group)
  const int wc = w & 3;         // 0..3  (N wave group)
  const int lr = l & 15;
  const int lk4 = l >> 4;       // 0..3
  const int l7 = l & 7;

  const unsigned short* Ag = X + (size_t)row0 * K_DIM;
  const unsigned short* Bg = W + (size_t)col0 * K_DIM;

  // staging geometry: thread t -> row rb+((t>>3)&31); global col16 pre-swizzled
  const int srl = (tid >> 3) & 31;
  const int sc16 = (tid & 7) ^ ((tid >> 3) & 7);      // inverse-swizzled source
  const int shi = tid >> 8;                           // wave-uniform chunk select
  const int slin = ((tid >> 3) & 24) * 64 + (tid & 63) * 8;  // linear LDS dest

  auto stage = [&](unsigned short* lbase, const unsigned short* gbase,
                   int rb0, int rb1, int tk) {
    int rb = shi ? rb1 : rb0;
    int trow = rb + srl;
    gload16(gbase + (size_t)trow * K_DIM + tk * BK + sc16 * 8,
            lbase + rb * 64 + slin);
  };

  auto rdA = [&](const unsigned short* base, int mf, int ks) -> bf16x8 {
    int trow = wr * 128 + mf * 16 + lr;
    int c16l = (ks * 4 + lk4) ^ l7;
    return *(const bf16x8*)&base[trow * 64 + c16l * 8];
  };
  auto rdB = [&](const unsigned short* base, int nf, int ks) -> bf16x8 {
    int trow = wc * 64 + nf * 16 + lr;
    int c16l = (ks * 4 + lk4) ^ l7;
    return *(const bf16x8*)&base[trow * 64 + c16l * 8];
  };

  f32x4 acc[8][4] = {};
  bf16x8 a0[4][2];   // a-mh0 fragments (read P2 for next tile)
  bf16x8 a1[4][2];   // a-mh1 fragments (read P1)
  bf16x8 bb[4][2];   // bb[0..1]=b01 (read P3), bb[2..3]=b23 (read P0)

#define PHASE_MFMA(AARR, MB, JB)                                              \
  __builtin_amdgcn_s_setprio(1);                                              \
  _Pragma("unroll") for (int i = 0; i < 4; ++i)                               \
  _Pragma("unroll") for (int jj = 0; jj < 2; ++jj)                            \
  _Pragma("unroll") for (int ks = 0; ks < 2; ++ks)                            \
      acc[(MB) + i][(JB) + jj] = __builtin_amdgcn_mfma_f32_16x16x32_bf16(     \
          AARR[i][ks], bb[(JB) + jj][ks], acc[(MB) + i][(JB) + jj], 0, 0, 0); \
  __builtin_amdgcn_s_setprio(0);

  // ---- prologue: issue order matters for vmcnt accounting
  stage(sA[0], Ag, 0, 32, 0);     // R0(0)
  stage(sA[0], Ag, 128, 160, 0);  // R1(0)
  stage(sB[0], Bg, 0, 64, 0);     // R2(0)
  stage(sB[0], Bg, 128, 192, 0);  // R3(0)
  stage(sB[0], Bg, 32, 96, 0);    // R4(0)
  stage(sB[0], Bg, 160, 224, 0);  // R5(0)
  stage(sA[0], Ag, 64, 96, 0);    // R6(0)
  stage(sA[0], Ag, 192, 224, 0);  // R7(0)
  stage(sA[1], Ag, 0, 32, 1);     // R0(1)
  stage(sA[1], Ag, 128, 160, 1);  // R1(1)
  stage(sB[1], Bg, 0, 64, 1);     // R2(1)
  stage(sB[1], Bg, 128, 192, 1);  // R3(1)
  VMCNT(8);                       // R0-R3(0) landed
  BAR();
  // pre-reads for P0(0)'s MFMA: a-mh0(0), b01(0)
#pragma unroll
  for (int i = 0; i < 4; ++i)
#pragma unroll
    for (int ks = 0; ks < 2; ++ks) a0[i][ks] = rdA(sA[0], i, ks);
#pragma unroll
  for (int j = 0; j < 2; ++j)
#pragma unroll
    for (int ks = 0; ks < 2; ++ks) bb[j][ks] = rdB(sB[0], j, ks);
  VMCNT(6);                       // R4,R5(0) landed (matches steady end-P3 gate)
  BAR();

  for (int t = 0; t < NT; ++t) {
    const int p = t & 1, q = p ^ 1;
    const int t1 = (t + 1) & (NT - 1);   // wrapped tail: uniform counting
    const int t2 = (t + 2) & (NT - 1);
    const unsigned short* pa = sA[p];
    const unsigned short* pb = sB[p];
    const unsigned short* qa = sA[q];
    const unsigned short* qb = sB[q];

    // ---- P0: read b23(t); stage R4R5(t+1); MFMA(mh0,nh0) on a0,b01
#pragma unroll
    for (int j = 2; j < 4; ++j)
#pragma unroll
      for (int ks = 0; ks < 2; ++ks) bb[j][ks] = rdB(pb, j, ks);
    stage(sB[q], Bg, 32, 96, t1);    // R4(t+1)
    stage(sB[q], Bg, 160, 224, t1);  // R5(t+1)
    PHASE_MFMA(a0, 0, 0);
    VMCNT(6);                        // retires R6R7(t)
    BAR();

    // ---- P1: read a-mh1(t); stage R6R7(t+1); MFMA(mh0,nh1) on a0,b23
#pragma unroll
    for (int i = 0; i < 4; ++i)
#pragma unroll
      for (int ks = 0; ks < 2; ++ks) a1[i][ks] = rdA(pa, 4 + i, ks);
    stage(sA[q], Ag, 64, 96, t1);    // R6(t+1)
    stage(sA[q], Ag, 192, 224, t1);  // R7(t+1)
    PHASE_MFMA(a0, 0, 2);
    VMCNT(6);                        // retires R0R1(t+1)
    BAR();

    // ---- P2: read a-mh0(t+1); stage R0R1(t+2); MFMA(mh1,nh0) on a1,b01
#pragma unroll
    for (int i = 0; i < 4; ++i)
#pragma unroll
      for (int ks = 0; ks < 2; ++ks) a0[i][ks] = rdA(qa, i, ks);
    stage(sA[p], Ag, 0, 32, t2);     // R0(t+2)
    stage(sA[p], Ag, 128, 160, t2);  // R1(t+2)
    PHASE_MFMA(a1, 4, 0);
    VMCNT(6);                        // retires R2R3(t+1)
    BAR();

    // ---- P3: read b01(t+1); stage R2R3(t+2); MFMA(mh1,nh1) on a1,b23
#pragma unroll
    for (int j = 0; j < 2; ++j)
#pragma unroll
      for (int ks = 0; ks < 2; ++ks) bb[j][ks] = rdB(qb, j, ks);
    stage(sB[p], Bg, 0, 64, t2);     // R2(t+2)
    stage(sB[p], Bg, 128, 192, t2);  // R3(t+2)
    PHASE_MFMA(a1, 4, 2);
    VMCNT(6);                        // retires R4R5(t+1)
    BAR();
  }

  // ---- epilogue: bias + store (C/D layout: col=lane&15, row=(lane>>4)*4+reg)
  float bv[4];
#pragma unroll
  for (int nf = 0; nf < 4; ++nf) bv[nf] = bias[col0 + wc * 64 + nf * 16 + lr];
  const int orow = lk4 * 4;
#pragma unroll
  for (int mf = 0; mf < 8; ++mf) {
#pragma unroll
    for (int nf = 0; nf < 4; ++nf) {
      const int colg = col0 + wc * 64 + nf * 16 + lr;
#pragma unroll
      for (int r = 0; r < 4; ++r) {
        int rowg = row0 + wr * 128 + mf * 16 + orow + r;
        out[(size_t)rowg * N_DIM + colg] = acc[mf][nf][r] + bv[nf];
      }
    }
  }
#undef PHASE_MFMA
}

// ---------------- launch ----------------
extern "C" void kernel_launch(void* const* d_in, const int* in_sizes, int n_in,
                              void* d_out, int out_size, void* d_ws, size_t ws_size,
                              hipStream_t stream) {
  const float* input  = (const float*)d_in[0];
  const float* pweight = (const float*)d_in[1];
  const float* nweight = (const float*)d_in[2];
  const float* exps   = (const float*)d_in[3];
  const float* bexps  = (const float*)d_in[4];
  const float* maskw  = (const float*)d_in[5];
  const float* scale  = (const float*)d_in[6];
  const float* pbias  = (const float*)d_in[7];
  const float* nbias  = (const float*)d_in[8];
  const float* bscale = (const float*)d_in[9];
  float* out = (float*)d_out;

  unsigned short* Xb = (unsigned short*)d_ws;                                        // 64 MB
  unsigned short* Wb = (unsigned short*)((char*)d_ws + (size_t)M_DIM * K_DIM * 2);   // 8 MB
  float* bias = (float*)((char*)d_ws + (size_t)M_DIM * K_DIM * 2 + (size_t)N_DIM * K_DIM * 2);

  convert_x<<<(M_DIM * (size_t)K_DIM) / 8 / 256, 256, 0, stream>>>((const float4*)input, (uint4*)Xb);
  make_w<<<((size_t)N_DIM * K_DIM) / 256, 256, 0, stream>>>(
      (const float4*)pweight, (const float4*)nweight, exps, maskw, scale, Wb);
  make_bias<<<(N_DIM + 255) / 256, 256, 0, stream>>>(pbias, nbias, bexps, bscale, bias);

  dim3 grid((M_DIM / BM) * (N_DIM / BN));   // 64 * 8 = 512
  gemm_bias<<<grid, 512, 0, stream>>>(Xb, Wb, bias, out);
}